// Round 7
// baseline (252.235 us; speedup 1.0000x reference)
//
#include <hip/hip_runtime.h>
#include <hip/hip_bf16.h>
#include <stdint.h>

#define N_NODES 100000
#define N_EDGES 1638400
#define IN_FEAT 128
#define OUT_FEAT 64
#define NUM_RELS 8

#define BUCKET_BITS 9
#define BUCKET_SIZE 512                       // nodes per bucket
#define NBUCKETS ((N_NODES + BUCKET_SIZE - 1) / BUCKET_SIZE)   // 196
#define ABLOCKS 200
#define AEDGES (N_EDGES / ABLOCKS)            // 8192 edges per bin block
#define APT (AEDGES / 1024)                   // 8 edges per thread
#define BK 12                                 // sortB: max 12288 edges/bucket (mean 8389, sigma 92)

// packed edge: src [0:16], rel [17:19], local-dst [20:28]
typedef __attribute__((ext_vector_type(8))) short short8;
typedef __attribute__((ext_vector_type(4))) short short4v;
typedef __attribute__((ext_vector_type(4))) float floatx4;

__device__ __forceinline__ unsigned short f2bf(float x) {
    union { float f; uint32_t u; } c; c.f = x;
    uint32_t u = c.u;
    u += 0x7FFFu + ((u >> 16) & 1u);   // RNE
    return (unsigned short)(u >> 16);
}

// ---------------- prep: zero bucketHist + cast W to bf16 ---------------------
#define W8 (NUM_RELS * OUT_FEAT * IN_FEAT / 8)   // 8192 short8 units
__global__ __launch_bounds__(256)
void prep_kernel(const float* __restrict__ W, unsigned short* __restrict__ W_bf,
                 int* __restrict__ bucketHist) {
    int u = blockIdx.x * 256 + threadIdx.x;
    if (u < NBUCKETS) bucketHist[u] = 0;
    int w = u - NBUCKETS;
    if (w >= 0 && w < W8) {
        const float* s = W + (size_t)w * 8;
        float4 a = *(const float4*)s, b = *(const float4*)(s + 4);
        short8 v;
        v[0] = f2bf(a.x); v[1] = f2bf(a.y); v[2] = f2bf(a.z); v[3] = f2bf(a.w);
        v[4] = f2bf(b.x); v[5] = f2bf(b.y); v[6] = f2bf(b.z); v[7] = f2bf(b.w);
        *(short8*)(W_bf + (size_t)w * 8) = v;
    }
}

// ---------------- A0: bucket histogram (LDS-staged) --------------------------
__global__ __launch_bounds__(1024)
void buckethist_kernel(const int* __restrict__ dst, int* __restrict__ bucketHist) {
    __shared__ int h[NBUCKETS];
    const int t = threadIdx.x;
    if (t < NBUCKETS) h[t] = 0;
    __syncthreads();
    #pragma unroll
    for (int i = 0; i < APT; ++i) {
        int e = blockIdx.x * AEDGES + i * 1024 + t;
        atomicAdd(&h[dst[e] >> BUCKET_BITS], 1);
    }
    __syncthreads();
    if (t < NBUCKETS && h[t] > 0) atomicAdd(&bucketHist[t], h[t]);
}

// ---------------- A1: scan 196 bucket totals (1 block) -----------------------
__global__ __launch_bounds__(256)
void bucketscan_kernel(const int* __restrict__ bucketHist, int* __restrict__ bucketStart,
                       int* __restrict__ bucketCursor) {
    __shared__ int wtot[4];
    const int t = threadIdx.x, lane = t & 63, wv = t >> 6;
    int v = (t < NBUCKETS) ? bucketHist[t] : 0;
    int x = v;
    #pragma unroll
    for (int d = 1; d < 64; d <<= 1) {
        int tv = __shfl_up(x, d, 64);
        if (lane >= d) x += tv;
    }
    if (lane == 63) wtot[wv] = x;
    __syncthreads();
    if (t == 0) {
        int run = 0;
        #pragma unroll
        for (int j = 0; j < 4; ++j) { int c = wtot[j]; wtot[j] = run; run += c; }
    }
    __syncthreads();
    int excl = x - v + wtot[wv];
    if (t < NBUCKETS) { bucketStart[t] = excl; bucketCursor[t] = excl; }
    if (t == 0) bucketStart[NBUCKETS] = N_EDGES;
}

// ---------------- A2: bin edges into exact bucket regions --------------------
__global__ __launch_bounds__(1024)
void bin_kernel(const int* __restrict__ src, const int* __restrict__ dst,
                const int* __restrict__ typ, int* __restrict__ bucketCursor,
                uint32_t* __restrict__ bins) {
    __shared__ int h[NBUCKETS];
    __shared__ int base[NBUCKETS];
    const int t = threadIdx.x;
    if (t < NBUCKETS) h[t] = 0;
    __syncthreads();
    uint32_t pk[APT]; int bk[APT], rk[APT];
    #pragma unroll
    for (int i = 0; i < APT; ++i) {
        int e = blockIdx.x * AEDGES + i * 1024 + t;
        int d = dst[e];
        int b = d >> BUCKET_BITS;
        bk[i] = b;
        pk[i] = ((uint32_t)(d & (BUCKET_SIZE - 1)) << 20) | ((uint32_t)typ[e] << 17) | (uint32_t)src[e];
        rk[i] = atomicAdd(&h[b], 1);
    }
    __syncthreads();
    if (t < NBUCKETS && h[t] > 0) base[t] = atomicAdd(&bucketCursor[t], h[t]);
    __syncthreads();
    #pragma unroll
    for (int i = 0; i < APT; ++i)
        bins[base[bk[i]] + rk[i]] = pk[i];
}

// ---------------- A3: per-bucket counting sort + packed CSR offs -------------
// offs[node] = (start << 8) | deg   (start < 2^24, deg <= ~45)
__global__ __launch_bounds__(1024)
void sortb_kernel(const int* __restrict__ bucketStart, uint32_t* __restrict__ bins,
                  int* __restrict__ offs) {
    __shared__ int cnt_l[BUCKET_SIZE];
    __shared__ int start_l[BUCKET_SIZE];
    __shared__ int wtot[8];
    const int b = blockIdx.x;
    const int t = threadIdx.x, lane = t & 63, wv = t >> 6;
    const int s = bucketStart[b];
    const int cnt = bucketStart[b + 1] - s;
    if (t < BUCKET_SIZE) cnt_l[t] = 0;
    __syncthreads();
    uint32_t pk[BK]; int rk[BK], ld[BK];
    #pragma unroll
    for (int k = 0; k < BK; ++k) {
        int idx = t + k * 1024;
        ld[k] = -1;
        if (idx < cnt) {
            uint32_t p = bins[s + idx];
            pk[k] = p;
            ld[k] = (int)(p >> 20);
            rk[k] = atomicAdd(&cnt_l[ld[k]], 1);
        }
    }
    __syncthreads();
    int v = 0, x = 0;
    if (t < BUCKET_SIZE) {
        v = cnt_l[t]; x = v;
        #pragma unroll
        for (int d = 1; d < 64; d <<= 1) {
            int tv = __shfl_up(x, d, 64);
            if (lane >= d) x += tv;
        }
        if (lane == 63) wtot[wv] = x;
    }
    __syncthreads();
    if (t == 0) {
        int run = 0;
        #pragma unroll
        for (int j = 0; j < 8; ++j) { int c = wtot[j]; wtot[j] = run; run += c; }
    }
    __syncthreads();
    if (t < BUCKET_SIZE) {
        int excl = x - v + wtot[wv];
        start_l[t] = excl;
        int node = b * BUCKET_SIZE + t;
        if (node < N_NODES) offs[node] = ((s + excl) << 8) | v;
    }
    __syncthreads();
    #pragma unroll
    for (int k = 0; k < BK; ++k)
        if (ld[k] >= 0)
            bins[s + start_l[ld[k]] + rk[k]] = pk[k];
}

// ---------------- transform: 512 thr, 8 waves, wave = rel --------------------
// feat tile (64 nodes) staged ONCE into LDS (bf16, padded rows); each wave
// computes one relation with W-fragments register-resident (W first operand:
// D row = channel, D col = node -> packed uint2 stores).
__global__ __launch_bounds__(512)
void transform_kernel(const float* __restrict__ feat,
                      const unsigned short* __restrict__ W_bf,
                      unsigned short* __restrict__ xw) {
    const int n0   = blockIdx.x * 64;
    const int t    = threadIdx.x;
    const int lane = t & 63;
    const int r    = t >> 6;               // wave = relation

    __shared__ unsigned short sA[64 * 136];

    // stage feat tile once: 2048 float4 units over 512 threads = 4 iters
    #pragma unroll
    for (int i = 0; i < 4; ++i) {
        int f4 = t + 512 * i;               // 0..2047
        int row = f4 >> 5, c4 = f4 & 31;
        int n = n0 + row;
        float4 v = (n < N_NODES) ? *(const float4*)(feat + (size_t)n * IN_FEAT + c4 * 4)
                                 : make_float4(0.f, 0.f, 0.f, 0.f);
        short4v p = { (short)f2bf(v.x), (short)f2bf(v.y), (short)f2bf(v.z), (short)f2bf(v.w) };
        *(short4v*)&sA[row * 136 + c4 * 4] = p;
    }
    __syncthreads();                        // the only barrier

    const int quad = lane >> 4;
    const int lrow = lane & 15;

    // W-fragments (first operand): rows = channels jm*16+lrow, k-contiguous
    short8 wfr[4][4];
    #pragma unroll
    for (int jm = 0; jm < 4; ++jm)
        #pragma unroll
        for (int kk = 0; kk < 4; ++kk)
            wfr[jm][kk] = *(const short8*)(W_bf +
                ((size_t)r * OUT_FEAT + jm * 16 + lrow) * IN_FEAT + kk * 32 + quad * 8);

    const bool full = (n0 + 64 <= N_NODES);

    #pragma unroll
    for (int nb = 0; nb < 4; ++nb) {
        floatx4 acc[4] = {{0,0,0,0},{0,0,0,0},{0,0,0,0},{0,0,0,0}};
        #pragma unroll
        for (int kk = 0; kk < 4; ++kk) {
            short8 bfrag = *(const short8*)&sA[(nb * 16 + lrow) * 136 + kk * 32 + quad * 8];
            #pragma unroll
            for (int jm = 0; jm < 4; ++jm)
                acc[jm] = __builtin_amdgcn_mfma_f32_16x16x32_bf16(wfr[jm][kk], bfrag, acc[jm], 0, 0, 0);
        }
        int n = n0 + nb * 16 + lrow;
        if (full || n < N_NODES) {
            unsigned short* rowp = xw + ((size_t)r * N_NODES + n) * OUT_FEAT;
            #pragma unroll
            for (int jm = 0; jm < 4; ++jm) {
                uint2 u;
                u.x = (uint32_t)f2bf(acc[jm][0]) | ((uint32_t)f2bf(acc[jm][1]) << 16);
                u.y = (uint32_t)f2bf(acc[jm][2]) | ((uint32_t)f2bf(acc[jm][3]) << 16);
                *(uint2*)(rowp + jm * 16 + quad * 4) = u;
            }
        }
    }
}

// ---------------- gather: 1 wave/node, 4 edges/iter, uint2 channel loads -----
__global__ __launch_bounds__(256)
void gather_kernel(const unsigned short* __restrict__ xw, const int* __restrict__ offs,
                   const uint32_t* __restrict__ bins, float* __restrict__ out) {
    const int wv = threadIdx.x >> 6;
    const int lane = threadIdx.x & 63;
    const int g = lane >> 4;
    const int l = lane & 15;
    const int node = blockIdx.x * 4 + wv;
    if (node >= N_NODES) return;
    const int pd = offs[node];
    const int start = pd >> 8;
    const int deg = pd & 255;
    float4 acc = make_float4(0.f, 0.f, 0.f, 0.f);
    for (int base = 0; base < deg; base += 64) {
        int rem = deg - base; if (rem > 64) rem = 64;
        uint32_t pl = bins[start + base + lane];   // batch packet preload (pad-guarded)
        int rounds = (rem + 3) >> 2;
        for (int i = 0; i < rounds; ++i) {
            int ei = i * 4 + g;
            uint32_t p = __shfl(pl, ei, 64);
            if (ei < rem) {
                int rel = (p >> 17) & 7;
                int src = (int)(p & 0x1FFFF);
                const uint2* q = (const uint2*)(xw + ((size_t)rel * N_NODES + src) * OUT_FEAT + l * 4);
                uint2 u = *q;
                union { uint32_t u; float f; } c0, c1, c2, c3;
                c0.u = u.x << 16; c1.u = u.x & 0xFFFF0000u;
                c2.u = u.y << 16; c3.u = u.y & 0xFFFF0000u;
                acc.x += c0.f; acc.y += c1.f; acc.z += c2.f; acc.w += c3.f;
            }
        }
    }
    acc.x += __shfl_xor(acc.x, 16, 64); acc.y += __shfl_xor(acc.y, 16, 64);
    acc.z += __shfl_xor(acc.z, 16, 64); acc.w += __shfl_xor(acc.w, 16, 64);
    acc.x += __shfl_xor(acc.x, 32, 64); acc.y += __shfl_xor(acc.y, 32, 64);
    acc.z += __shfl_xor(acc.z, 32, 64); acc.w += __shfl_xor(acc.w, 32, 64);
    if (g == 0)
        *(float4*)(out + (size_t)node * OUT_FEAT + l * 4) = acc;  // 16 lanes x 16 B
}

extern "C" void kernel_launch(void* const* d_in, const int* in_sizes, int n_in,
                              void* d_out, int out_size, void* d_ws, size_t ws_size,
                              hipStream_t stream) {
    const float* feat = (const float*)d_in[0];
    const float* W    = (const float*)d_in[1];
    const int* esrc   = (const int*)d_in[2];
    const int* edst   = (const int*)d_in[3];
    const int* etyp   = (const int*)d_in[4];
    float* out = (float*)d_out;

    // ws layout (~109.5 MB, within round-1's proven footprint)
    char* ws = (char*)d_ws;
    size_t ofs = 0;
    unsigned short* xw = (unsigned short*)(ws + ofs);
    ofs += (size_t)NUM_RELS * N_NODES * OUT_FEAT * 2;           // 102,400,000
    unsigned short* W_bf = (unsigned short*)(ws + ofs);
    ofs += (size_t)NUM_RELS * OUT_FEAT * IN_FEAT * 2;           // 131,072
    uint32_t* bins = (uint32_t*)(ws + ofs);
    ofs += (size_t)N_EDGES * 4 + 256;                           // 6,553,600 + overrun pad
    int* offs = (int*)(ws + ofs);
    ofs += ((size_t)N_NODES * 4 + 255) & ~(size_t)255;          // 400,000
    int* bucketHist = (int*)(ws + ofs);   ofs += 1024;
    int* bucketStart = (int*)(ws + ofs);  ofs += 1024;          // NBUCKETS+1 ints
    int* bucketCursor = (int*)(ws + ofs); ofs += 1024;

    prep_kernel<<<(NBUCKETS + W8 + 255) / 256, 256, 0, stream>>>(W, W_bf, bucketHist);
    buckethist_kernel<<<ABLOCKS, 1024, 0, stream>>>(edst, bucketHist);
    bucketscan_kernel<<<1, 256, 0, stream>>>(bucketHist, bucketStart, bucketCursor);
    bin_kernel<<<ABLOCKS, 1024, 0, stream>>>(esrc, edst, etyp, bucketCursor, bins);
    sortb_kernel<<<NBUCKETS, 1024, 0, stream>>>(bucketStart, bins, offs);
    transform_kernel<<<(N_NODES + 63) / 64, 512, 0, stream>>>(feat, W_bf, xw);
    gather_kernel<<<(N_NODES + 3) / 4, 256, 0, stream>>>(xw, offs, bins, out);
}

// Round 8
// 230.142 us; speedup vs baseline: 1.0960x; 1.0960x over previous
//
#include <hip/hip_runtime.h>
#include <hip/hip_bf16.h>
#include <stdint.h>

#define N_NODES 100000
#define N_EDGES 1638400
#define IN_FEAT 128
#define OUT_FEAT 64
#define NUM_RELS 8
#define NTILES ((N_NODES + 63) / 64)          // 1563
#define TGRID 512                             // transform blocks; ~3 tiles each

#define BUCKET_BITS 9
#define BUCKET_SIZE 512                       // nodes per bucket
#define NBUCKETS ((N_NODES + BUCKET_SIZE - 1) / BUCKET_SIZE)   // 196
#define ABLOCKS 200
#define AEDGES (N_EDGES / ABLOCKS)            // 8192 edges per bin block
#define APT (AEDGES / 1024)                   // 8 edges per thread
#define BK 12                                 // sortB: max 12288 edges/bucket (mean 8389, sigma 92)

// packed edge: src [0:16], rel [17:19], local-dst [20:28]
typedef __attribute__((ext_vector_type(8))) short short8;
typedef __attribute__((ext_vector_type(4))) short short4v;
typedef __attribute__((ext_vector_type(4))) float floatx4;

__device__ __forceinline__ unsigned short f2bf(float x) {
    union { float f; uint32_t u; } c; c.f = x;
    uint32_t u = c.u;
    u += 0x7FFFu + ((u >> 16) & 1u);   // RNE
    return (unsigned short)(u >> 16);
}

// ---------------- prep: zero bucketHist + cast W to bf16 ---------------------
#define W8 (NUM_RELS * OUT_FEAT * IN_FEAT / 8)   // 8192 short8 units
__global__ __launch_bounds__(256)
void prep_kernel(const float* __restrict__ W, unsigned short* __restrict__ W_bf,
                 int* __restrict__ bucketHist) {
    int u = blockIdx.x * 256 + threadIdx.x;
    if (u < NBUCKETS) bucketHist[u] = 0;
    int w = u - NBUCKETS;
    if (w >= 0 && w < W8) {
        const float* s = W + (size_t)w * 8;
        float4 a = *(const float4*)s, b = *(const float4*)(s + 4);
        short8 v;
        v[0] = f2bf(a.x); v[1] = f2bf(a.y); v[2] = f2bf(a.z); v[3] = f2bf(a.w);
        v[4] = f2bf(b.x); v[5] = f2bf(b.y); v[6] = f2bf(b.z); v[7] = f2bf(b.w);
        *(short8*)(W_bf + (size_t)w * 8) = v;
    }
}

// ---------------- A0: bucket histogram (LDS-staged) --------------------------
__global__ __launch_bounds__(1024)
void buckethist_kernel(const int* __restrict__ dst, int* __restrict__ bucketHist) {
    __shared__ int h[NBUCKETS];
    const int t = threadIdx.x;
    if (t < NBUCKETS) h[t] = 0;
    __syncthreads();
    #pragma unroll
    for (int i = 0; i < APT; ++i) {
        int e = blockIdx.x * AEDGES + i * 1024 + t;
        atomicAdd(&h[dst[e] >> BUCKET_BITS], 1);
    }
    __syncthreads();
    if (t < NBUCKETS && h[t] > 0) atomicAdd(&bucketHist[t], h[t]);
}

// ---------------- A1: scan 196 bucket totals (1 block) -----------------------
__global__ __launch_bounds__(256)
void bucketscan_kernel(const int* __restrict__ bucketHist, int* __restrict__ bucketStart,
                       int* __restrict__ bucketCursor) {
    __shared__ int wtot[4];
    const int t = threadIdx.x, lane = t & 63, wv = t >> 6;
    int v = (t < NBUCKETS) ? bucketHist[t] : 0;
    int x = v;
    #pragma unroll
    for (int d = 1; d < 64; d <<= 1) {
        int tv = __shfl_up(x, d, 64);
        if (lane >= d) x += tv;
    }
    if (lane == 63) wtot[wv] = x;
    __syncthreads();
    if (t == 0) {
        int run = 0;
        #pragma unroll
        for (int j = 0; j < 4; ++j) { int c = wtot[j]; wtot[j] = run; run += c; }
    }
    __syncthreads();
    int excl = x - v + wtot[wv];
    if (t < NBUCKETS) { bucketStart[t] = excl; bucketCursor[t] = excl; }
    if (t == 0) bucketStart[NBUCKETS] = N_EDGES;
}

// ---------------- A2: bin edges into exact bucket regions --------------------
__global__ __launch_bounds__(1024)
void bin_kernel(const int* __restrict__ src, const int* __restrict__ dst,
                const int* __restrict__ typ, int* __restrict__ bucketCursor,
                uint32_t* __restrict__ bins) {
    __shared__ int h[NBUCKETS];
    __shared__ int base[NBUCKETS];
    const int t = threadIdx.x;
    if (t < NBUCKETS) h[t] = 0;
    __syncthreads();
    uint32_t pk[APT]; int bk[APT], rk[APT];
    #pragma unroll
    for (int i = 0; i < APT; ++i) {
        int e = blockIdx.x * AEDGES + i * 1024 + t;
        int d = dst[e];
        int b = d >> BUCKET_BITS;
        bk[i] = b;
        pk[i] = ((uint32_t)(d & (BUCKET_SIZE - 1)) << 20) | ((uint32_t)typ[e] << 17) | (uint32_t)src[e];
        rk[i] = atomicAdd(&h[b], 1);
    }
    __syncthreads();
    if (t < NBUCKETS && h[t] > 0) base[t] = atomicAdd(&bucketCursor[t], h[t]);
    __syncthreads();
    #pragma unroll
    for (int i = 0; i < APT; ++i)
        bins[base[bk[i]] + rk[i]] = pk[i];
}

// ---------------- A3: per-bucket counting sort + packed CSR offs -------------
// offs[node] = (start << 8) | deg   (start < 2^24, deg <= ~45)
__global__ __launch_bounds__(1024)
void sortb_kernel(const int* __restrict__ bucketStart, uint32_t* __restrict__ bins,
                  int* __restrict__ offs) {
    __shared__ int cnt_l[BUCKET_SIZE];
    __shared__ int start_l[BUCKET_SIZE];
    __shared__ int wtot[8];
    const int b = blockIdx.x;
    const int t = threadIdx.x, lane = t & 63, wv = t >> 6;
    const int s = bucketStart[b];
    const int cnt = bucketStart[b + 1] - s;
    if (t < BUCKET_SIZE) cnt_l[t] = 0;
    __syncthreads();
    uint32_t pk[BK]; int rk[BK], ld[BK];
    #pragma unroll
    for (int k = 0; k < BK; ++k) {
        int idx = t + k * 1024;
        ld[k] = -1;
        if (idx < cnt) {
            uint32_t p = bins[s + idx];
            pk[k] = p;
            ld[k] = (int)(p >> 20);
            rk[k] = atomicAdd(&cnt_l[ld[k]], 1);
        }
    }
    __syncthreads();
    int v = 0, x = 0;
    if (t < BUCKET_SIZE) {
        v = cnt_l[t]; x = v;
        #pragma unroll
        for (int d = 1; d < 64; d <<= 1) {
            int tv = __shfl_up(x, d, 64);
            if (lane >= d) x += tv;
        }
        if (lane == 63) wtot[wv] = x;
    }
    __syncthreads();
    if (t == 0) {
        int run = 0;
        #pragma unroll
        for (int j = 0; j < 8; ++j) { int c = wtot[j]; wtot[j] = run; run += c; }
    }
    __syncthreads();
    if (t < BUCKET_SIZE) {
        int excl = x - v + wtot[wv];
        start_l[t] = excl;
        int node = b * BUCKET_SIZE + t;
        if (node < N_NODES) offs[node] = ((s + excl) << 8) | v;
    }
    __syncthreads();
    #pragma unroll
    for (int k = 0; k < BK; ++k)
        if (ld[k] >= 0)
            bins[s + start_l[ld[k]] + rk[k]] = pk[k];
}

// ---------------- transform: persistent blocks, double-buffered tiles --------
// 512 thr (8 waves, wave = rel); each block loops ~3 node tiles; W-fragments
// register-resident once per block; LDS ping-pong, ONE barrier per tile; next
// tile's feat loads issue before current tile's compute (sw pipeline).
__global__ __launch_bounds__(512)
void transform_kernel(const float* __restrict__ feat,
                      const unsigned short* __restrict__ W_bf,
                      unsigned short* __restrict__ xw) {
    const int t    = threadIdx.x;
    const int lane = t & 63;
    const int r    = t >> 6;               // wave = relation
    const int quad = lane >> 4;
    const int lrow = lane & 15;

    __shared__ unsigned short sA[2][64 * 136];

    // W-fragments (first operand): rows = channels jm*16+lrow, k-contiguous
    short8 wfr[4][4];
    #pragma unroll
    for (int jm = 0; jm < 4; ++jm)
        #pragma unroll
        for (int kk = 0; kk < 4; ++kk)
            wfr[jm][kk] = *(const short8*)(W_bf +
                ((size_t)r * OUT_FEAT + jm * 16 + lrow) * IN_FEAT + kk * 32 + quad * 8);

    int tile = blockIdx.x;

    // stage first tile into sA[0]
    #pragma unroll
    for (int i = 0; i < 4; ++i) {
        int f4 = t + 512 * i;               // 0..2047
        int row = f4 >> 5, c4 = f4 & 31;
        int n = tile * 64 + row;
        float4 v = (n < N_NODES) ? *(const float4*)(feat + (size_t)n * IN_FEAT + c4 * 4)
                                 : make_float4(0.f, 0.f, 0.f, 0.f);
        short4v p = { (short)f2bf(v.x), (short)f2bf(v.y), (short)f2bf(v.z), (short)f2bf(v.w) };
        *(short4v*)&sA[0][row * 136 + c4 * 4] = p;
    }

    int p = 0;
    while (tile < NTILES) {
        __syncthreads();                    // sA[p] staged; sA[p^1] fully consumed
        int nxt = tile + TGRID;
        if (nxt < NTILES) {
            #pragma unroll
            for (int i = 0; i < 4; ++i) {
                int f4 = t + 512 * i;
                int row = f4 >> 5, c4 = f4 & 31;
                int n = nxt * 64 + row;
                float4 v = (n < N_NODES) ? *(const float4*)(feat + (size_t)n * IN_FEAT + c4 * 4)
                                         : make_float4(0.f, 0.f, 0.f, 0.f);
                short4v q = { (short)f2bf(v.x), (short)f2bf(v.y), (short)f2bf(v.z), (short)f2bf(v.w) };
                *(short4v*)&sA[p ^ 1][row * 136 + c4 * 4] = q;
            }
        }

        const int n0 = tile * 64;
        const bool full = (n0 + 64 <= N_NODES);
        #pragma unroll
        for (int nb = 0; nb < 4; ++nb) {
            floatx4 acc[4] = {{0,0,0,0},{0,0,0,0},{0,0,0,0},{0,0,0,0}};
            #pragma unroll
            for (int kk = 0; kk < 4; ++kk) {
                short8 bfrag = *(const short8*)&sA[p][(nb * 16 + lrow) * 136 + kk * 32 + quad * 8];
                #pragma unroll
                for (int jm = 0; jm < 4; ++jm)
                    acc[jm] = __builtin_amdgcn_mfma_f32_16x16x32_bf16(wfr[jm][kk], bfrag, acc[jm], 0, 0, 0);
            }
            int n = n0 + nb * 16 + lrow;
            if (full || n < N_NODES) {
                unsigned short* rowp = xw + ((size_t)r * N_NODES + n) * OUT_FEAT;
                #pragma unroll
                for (int jm = 0; jm < 4; ++jm) {
                    uint2 u;
                    u.x = (uint32_t)f2bf(acc[jm][0]) | ((uint32_t)f2bf(acc[jm][1]) << 16);
                    u.y = (uint32_t)f2bf(acc[jm][2]) | ((uint32_t)f2bf(acc[jm][3]) << 16);
                    *(uint2*)(rowp + jm * 16 + quad * 4) = u;
                }
            }
        }
        p ^= 1;
        tile = nxt;
    }
}

// ---------------- gather: 1 wave/node, 4 edges/iter, uint2 channel loads -----
__global__ __launch_bounds__(256)
void gather_kernel(const unsigned short* __restrict__ xw, const int* __restrict__ offs,
                   const uint32_t* __restrict__ bins, float* __restrict__ out) {
    const int wv = threadIdx.x >> 6;
    const int lane = threadIdx.x & 63;
    const int g = lane >> 4;
    const int l = lane & 15;
    const int node = blockIdx.x * 4 + wv;
    if (node >= N_NODES) return;
    const int pd = offs[node];
    const int start = pd >> 8;
    const int deg = pd & 255;
    float4 acc = make_float4(0.f, 0.f, 0.f, 0.f);
    for (int base = 0; base < deg; base += 64) {
        int rem = deg - base; if (rem > 64) rem = 64;
        uint32_t pl = bins[start + base + lane];   // batch packet preload (pad-guarded)
        int rounds = (rem + 3) >> 2;
        for (int i = 0; i < rounds; ++i) {
            int ei = i * 4 + g;
            uint32_t p = __shfl(pl, ei, 64);
            if (ei < rem) {
                int rel = (p >> 17) & 7;
                int src = (int)(p & 0x1FFFF);
                const uint2* q = (const uint2*)(xw + ((size_t)rel * N_NODES + src) * OUT_FEAT + l * 4);
                uint2 u = *q;
                union { uint32_t u; float f; } c0, c1, c2, c3;
                c0.u = u.x << 16; c1.u = u.x & 0xFFFF0000u;
                c2.u = u.y << 16; c3.u = u.y & 0xFFFF0000u;
                acc.x += c0.f; acc.y += c1.f; acc.z += c2.f; acc.w += c3.f;
            }
        }
    }
    acc.x += __shfl_xor(acc.x, 16, 64); acc.y += __shfl_xor(acc.y, 16, 64);
    acc.z += __shfl_xor(acc.z, 16, 64); acc.w += __shfl_xor(acc.w, 16, 64);
    acc.x += __shfl_xor(acc.x, 32, 64); acc.y += __shfl_xor(acc.y, 32, 64);
    acc.z += __shfl_xor(acc.z, 32, 64); acc.w += __shfl_xor(acc.w, 32, 64);
    if (g == 0)
        *(float4*)(out + (size_t)node * OUT_FEAT + l * 4) = acc;  // 16 lanes x 16 B
}

extern "C" void kernel_launch(void* const* d_in, const int* in_sizes, int n_in,
                              void* d_out, int out_size, void* d_ws, size_t ws_size,
                              hipStream_t stream) {
    const float* feat = (const float*)d_in[0];
    const float* W    = (const float*)d_in[1];
    const int* esrc   = (const int*)d_in[2];
    const int* edst   = (const int*)d_in[3];
    const int* etyp   = (const int*)d_in[4];
    float* out = (float*)d_out;

    // ws layout (~109.5 MB, within round-1's proven footprint)
    char* ws = (char*)d_ws;
    size_t ofs = 0;
    unsigned short* xw = (unsigned short*)(ws + ofs);
    ofs += (size_t)NUM_RELS * N_NODES * OUT_FEAT * 2;           // 102,400,000
    unsigned short* W_bf = (unsigned short*)(ws + ofs);
    ofs += (size_t)NUM_RELS * OUT_FEAT * IN_FEAT * 2;           // 131,072
    uint32_t* bins = (uint32_t*)(ws + ofs);
    ofs += (size_t)N_EDGES * 4 + 256;                           // 6,553,600 + overrun pad
    int* offs = (int*)(ws + ofs);
    ofs += ((size_t)N_NODES * 4 + 255) & ~(size_t)255;          // 400,000
    int* bucketHist = (int*)(ws + ofs);   ofs += 1024;
    int* bucketStart = (int*)(ws + ofs);  ofs += 1024;          // NBUCKETS+1 ints
    int* bucketCursor = (int*)(ws + ofs); ofs += 1024;

    prep_kernel<<<(NBUCKETS + W8 + 255) / 256, 256, 0, stream>>>(W, W_bf, bucketHist);
    buckethist_kernel<<<ABLOCKS, 1024, 0, stream>>>(edst, bucketHist);
    bucketscan_kernel<<<1, 256, 0, stream>>>(bucketHist, bucketStart, bucketCursor);
    bin_kernel<<<ABLOCKS, 1024, 0, stream>>>(esrc, edst, etyp, bucketCursor, bins);
    sortb_kernel<<<NBUCKETS, 1024, 0, stream>>>(bucketStart, bins, offs);
    transform_kernel<<<TGRID, 512, 0, stream>>>(feat, W_bf, xw);
    gather_kernel<<<(N_NODES + 3) / 4, 256, 0, stream>>>(xw, offs, bins, out);
}